// Round 7
// baseline (64.199 us; speedup 1.0000x reference)
//
#include <hip/hip_runtime.h>
#include <math.h>

#define B 8
#define N 2048
#define DIM 32
#define HID 64
#define KLIFT 16
#define DMODEL 256
#define KPROXY 16
#define KSEL 8.0f

typedef float f32x4 __attribute__((ext_vector_type(4)));
typedef short bf16x8 __attribute__((ext_vector_type(8)));

__device__ inline unsigned short f2bf(float f) {
  unsigned u = __float_as_uint(f);
  unsigned r = (u + 0x7FFFu + ((u >> 16) & 1u)) >> 16;  // RNE
  return (unsigned short)r;
}
__device__ inline float bf2f(unsigned short s) {
  return __uint_as_float(((unsigned)s) << 16);
}
__device__ inline float clip_temp(float lt) {
  return fminf(fmaxf(expf(lt), 0.1f), 10.f);
}

// ---------------- K1: saliency MLP + sq + bf16 hi/lo split + budget1 partials + nnd2 init
// VERBATIM from round-4 passing build (bitwise-identical outputs).
__global__ __launch_bounds__(256) void k_prep(
    const float* __restrict__ x, const float* __restrict__ W1,
    const float* __restrict__ b1, const float* __restrict__ W2,
    const float* __restrict__ b2, const float* __restrict__ logt,
    float* __restrict__ sal, float* __restrict__ sq,
    unsigned short* __restrict__ Xhi, unsigned short* __restrict__ Xlo,
    float* __restrict__ partials1, unsigned* __restrict__ nnd2) {
  __shared__ float sW1[DIM * HID];
  __shared__ float sW2[HID], sb1[HID];
  __shared__ float red[4];
  int t = threadIdx.x;
  int lane = t & 63, wid = t >> 6;
  {
    const float4* s4 = (const float4*)W1;
    float4* d4 = (float4*)sW1;
    for (int i = t; i < DIM * HID / 4; i += 256) d4[i] = s4[i];
    if (t < HID) { sW2[t] = W2[t]; sb1[t] = b1[t]; }
  }
  __syncthreads();
  int p = blockIdx.x * 256 + t;       // 0..16383
  nnd2[p] = 0x7F7F7F7Fu;              // huge positive float bits
  float xr[DIM];
  const float4* xp = (const float4*)(x + (size_t)p * DIM);
#pragma unroll
  for (int i = 0; i < DIM / 4; i++) {
    float4 v = xp[i];
    xr[4 * i + 0] = v.x; xr[4 * i + 1] = v.y; xr[4 * i + 2] = v.z; xr[4 * i + 3] = v.w;
  }
  float s = 0.f;
#pragma unroll
  for (int d = 0; d < DIM; d++) s = fmaf(xr[d], xr[d], s);
  sq[p] = s;
  float h[HID];
#pragma unroll
  for (int j = 0; j < HID; j++) h[j] = sb1[j];
  for (int d = 0; d < DIM; d++) {
    float xv = xr[d];
    const float4* wrow = (const float4*)(&sW1[d * HID]);
#pragma unroll
    for (int j4 = 0; j4 < HID / 4; j4++) {
      float4 w = wrow[j4];
      h[4 * j4 + 0] = fmaf(xv, w.x, h[4 * j4 + 0]);
      h[4 * j4 + 1] = fmaf(xv, w.y, h[4 * j4 + 1]);
      h[4 * j4 + 2] = fmaf(xv, w.z, h[4 * j4 + 2]);
      h[4 * j4 + 3] = fmaf(xv, w.w, h[4 * j4 + 3]);
    }
  }
  float acc = b2[0];
#pragma unroll
  for (int j = 0; j < HID; j++) acc = fmaf(fmaxf(h[j], 0.f), sW2[j], acc);
  sal[p] = acc;
  // budget1 partial
  float temp = clip_temp(logt[0]);
  float y0 = 1.f / (1.f + expf(-((acc - 0.5f) / temp)));
  float part = y0;
#pragma unroll
  for (int off = 32; off >= 1; off >>= 1) part += __shfl_xor(part, off);
  if (lane == 0) red[wid] = part;
  __syncthreads();
  if (t == 0) partials1[blockIdx.x] = red[0] + red[1] + red[2] + red[3];
  // fragment-order bf16 split: lane L = g*16+c of tile holds X[tile*16+c][g*8+j]
  int bb = p >> 11, n = p & (N - 1);
  int tile = n >> 4, c = n & 15;
  size_t tb = ((size_t)(bb * 128 + tile)) * 64;
#pragma unroll
  for (int g = 0; g < 4; g++) {
    bf16x8 hv, lv;
#pragma unroll
    for (int j = 0; j < 8; j++) {
      float v = xr[g * 8 + j];
      unsigned short hb = f2bf(v);
      hv[j] = (short)hb;
      lv[j] = (short)f2bf(v - bf2f(hb));
    }
    size_t off = (tb + (size_t)g * 16 + c) * 8;
    *(bf16x8*)(Xhi + off) = hv;
    *(bf16x8*)(Xlo + off) = lv;
  }
}

// ---------------- K2: NN squared distance via split-bf16 MFMA Gram ----------------
// VERBATIM from round-4 passing build.
__global__ __launch_bounds__(256) void k_nnd(
    const unsigned short* __restrict__ Xhi, const unsigned short* __restrict__ Xlo,
    const float* __restrict__ sq, unsigned* __restrict__ nnd2) {
  int bid = blockIdx.x;
  int bb = bid >> 7;
  int nch = (bid >> 3) & 15;
  int mo = bid & 7;
  int t = threadIdx.x;
  int w = t >> 6, lane = t & 63;
  int c = lane & 15, g = lane >> 4;
  __shared__ unsigned short ldsH[16 * 512];
  __shared__ unsigned short ldsL[16 * 512];
  __shared__ float ssq[256];
  {
    size_t base = ((size_t)(bb * 128 + mo * 16)) * 512;
    const float4* srcH = (const float4*)(Xhi + base);
    const float4* srcL = (const float4*)(Xlo + base);
    float4* dH = (float4*)ldsH;
    float4* dL = (float4*)ldsL;
    for (int i = t; i < 1024; i += 256) { dH[i] = srcH[i]; dL[i] = srcL[i]; }
    ssq[t] = sq[bb * N + mo * 256 + t];
  }
  int nt0 = nch * 8 + w * 2, nt1 = nt0 + 1;
  bf16x8 ah0 = *(const bf16x8*)(Xhi + (((size_t)(bb * 128 + nt0)) * 64 + lane) * 8);
  bf16x8 al0 = *(const bf16x8*)(Xlo + (((size_t)(bb * 128 + nt0)) * 64 + lane) * 8);
  bf16x8 ah1 = *(const bf16x8*)(Xhi + (((size_t)(bb * 128 + nt1)) * 64 + lane) * 8);
  bf16x8 al1 = *(const bf16x8*)(Xlo + (((size_t)(bb * 128 + nt1)) * 64 + lane) * 8);
  __syncthreads();
  float mn0[4] = {1e30f, 1e30f, 1e30f, 1e30f};
  float mn1[4] = {1e30f, 1e30f, 1e30f, 1e30f};
  for (int tt = 0; tt < 16; tt++) {
    bf16x8 bh = ((const bf16x8*)(ldsH + tt * 512))[lane];
    bf16x8 bl2 = ((const bf16x8*)(ldsL + tt * 512))[lane];
    f32x4 a0 = {0.f, 0.f, 0.f, 0.f};
    f32x4 a1 = {0.f, 0.f, 0.f, 0.f};
    a0 = __builtin_amdgcn_mfma_f32_16x16x32_bf16(ah0, bh, a0, 0, 0, 0);
    a1 = __builtin_amdgcn_mfma_f32_16x16x32_bf16(ah1, bh, a1, 0, 0, 0);
    a0 = __builtin_amdgcn_mfma_f32_16x16x32_bf16(ah0, bl2, a0, 0, 0, 0);
    a1 = __builtin_amdgcn_mfma_f32_16x16x32_bf16(ah1, bl2, a1, 0, 0, 0);
    a0 = __builtin_amdgcn_mfma_f32_16x16x32_bf16(al0, bh, a0, 0, 0, 0);
    a1 = __builtin_amdgcn_mfma_f32_16x16x32_bf16(al1, bh, a1, 0, 0, 0);
    float sm = ssq[tt * 16 + c];
    int mtg = mo * 16 + tt;
    bool d0 = (mtg == nt0), d1 = (mtg == nt1);
#pragma unroll
    for (int r = 0; r < 4; r++) {
      float v0 = fmaf(-2.f, a0[r], sm);
      float v1 = fmaf(-2.f, a1[r], sm);
      if (d0 && c == 4 * g + r) v0 = 1e30f;   // mask self-distance
      if (d1 && c == 4 * g + r) v1 = 1e30f;
      mn0[r] = fminf(mn0[r], v0);
      mn1[r] = fminf(mn1[r], v1);
    }
  }
#pragma unroll
  for (int off = 1; off <= 8; off <<= 1) {
#pragma unroll
    for (int r = 0; r < 4; r++) {
      mn0[r] = fminf(mn0[r], __shfl_xor(mn0[r], off));
      mn1[r] = fminf(mn1[r], __shfl_xor(mn1[r], off));
    }
  }
  if (c == 0) {
#pragma unroll
    for (int r = 0; r < 4; r++) {
      int n0 = nt0 * 16 + 4 * g + r;
      float v = fmaxf(sq[bb * N + n0] + mn0[r], 0.f);
      atomicMin(&nnd2[bb * N + n0], __float_as_uint(v));
      int n1 = nt1 * 16 + 4 * g + r;
      v = fmaxf(sq[bb * N + n1] + mn1[r], 0.f);
      atomicMin(&nnd2[bb * N + n1], __float_as_uint(v));
    }
  }
}

// ---------------- K3: fused selector (R4 addition trees; LDS-staged tokens fix) ----------------
// 8 blocks x 1024 threads. Thread t owns points t (chunks 0-3) and t+1024 (chunks 4-7).
__global__ __launch_bounds__(1024) void k_sel3(
    const float* __restrict__ x, const float* __restrict__ sal,
    const float* __restrict__ sq, const unsigned* __restrict__ nnd2,
    const float* __restrict__ logt, const float* __restrict__ partials1,
    const float* __restrict__ mu, const float* __restrict__ sigma,
    const float* __restrict__ Wl, const float* __restrict__ bl,
    const float* __restrict__ Wp, const float* __restrict__ bp,
    float* __restrict__ tok, float* __restrict__ ystar) {
  int bb = blockIdx.x, t = threadIdx.x;
  int lane = t & 63, wid = t >> 6;   // 16 waves
  __shared__ float csf[1024];        // cn for the 4 chunks of the current pass
  __shared__ float gshf[4][8][32];
  __shared__ float red32f[16], red33f[16];
  __shared__ float gpartS[8][36];
  __shared__ float gfin[34];
  __shared__ float red2[32];
  __shared__ float bsh;
  __shared__ float yv[N];
  __shared__ float candv[256];
  __shared__ int candi[256];
  __shared__ int tix[KPROXY];
  __shared__ float sz[KPROXY][36];
  size_t base = (size_t)bb * N;
  float temp = clip_temp(logt[0]);
  // scale1: same sequential sum as R4 k_c1/k_c
  float b1v = 0.f;
  for (int j = 0; j < 8; j++) b1v += partials1[bb * 8 + j];
  float scale1 = fminf(KSEL / fmaxf(b1v, 1e-6f), 1.f);

  // ---- PASS 0: chunks 0..3 (point p0 = t) — replicate k_c1 trees ----
  float svA, dvA, nrmA, y1A;
  {
    int n = t;                         // chunk ch = t>>8, tt = t&255
    float sv = sal[base + n];
    float y0 = 1.f / (1.f + expf(-((sv - 0.5f) / temp)));
    float y1 = y0 * scale1;
    float dv = sqrtf(__uint_as_float(nnd2[base + n]));
    float nrm = sqrtf(sq[base + n] + 3.f * dv * dv + sv * sv) + 1e-8f;
    float cn = y1 / nrm;
    csf[t] = cn;
    svA = sv; dvA = dv; nrmA = nrm; y1A = y1;
    float v32 = cn * dv, v33 = cn * sv;
#pragma unroll
    for (int off = 32; off >= 1; off >>= 1) {
      v32 += __shfl_xor(v32, off);
      v33 += __shfl_xor(v33, off);
    }
    if (lane == 0) { red32f[wid] = v32; red33f[wid] = v33; }
  }
  __syncthreads();
  {
    int ch = t >> 8, pg = (t >> 5) & 7, d = t & 31;
    const float* xc = x + (base + (size_t)ch * 256 + pg * 32) * DIM + d;
    float acc = 0.f;
#pragma unroll
    for (int i = 0; i < 32; i++) acc = fmaf(csf[ch * 256 + pg * 32 + i], xc[i * DIM], acc);
    gshf[ch][pg][d] = acc;
  }
  __syncthreads();
  {
    int ch = t >> 8, tt = t & 255;
    if (tt < 32) {
      float s = 0.f;
#pragma unroll
      for (int pgi = 0; pgi < 8; pgi++) s += gshf[ch][pgi][tt];
      gpartS[ch][tt] = s;
    }
    if (tt == 0) {
      gpartS[ch][32] = red32f[4 * ch] + red32f[4 * ch + 1] + red32f[4 * ch + 2] + red32f[4 * ch + 3];
      gpartS[ch][33] = red33f[4 * ch] + red33f[4 * ch + 1] + red33f[4 * ch + 2] + red33f[4 * ch + 3];
    }
  }
  __syncthreads();

  // ---- PASS 1: chunks 4..7 (point p1 = t + 1024) ----
  float svB, dvB, nrmB, y1B;
  {
    int n = t + 1024;
    float sv = sal[base + n];
    float y0 = 1.f / (1.f + expf(-((sv - 0.5f) / temp)));
    float y1 = y0 * scale1;
    float dv = sqrtf(__uint_as_float(nnd2[base + n]));
    float nrm = sqrtf(sq[base + n] + 3.f * dv * dv + sv * sv) + 1e-8f;
    float cn = y1 / nrm;
    csf[t] = cn;
    svB = sv; dvB = dv; nrmB = nrm; y1B = y1;
    float v32 = cn * dv, v33 = cn * sv;
#pragma unroll
    for (int off = 32; off >= 1; off >>= 1) {
      v32 += __shfl_xor(v32, off);
      v33 += __shfl_xor(v33, off);
    }
    if (lane == 0) { red32f[wid] = v32; red33f[wid] = v33; }
  }
  __syncthreads();
  {
    int ch4 = t >> 8, pg = (t >> 5) & 7, d = t & 31;
    const float* xc = x + (base + 1024 + (size_t)ch4 * 256 + pg * 32) * DIM + d;
    float acc = 0.f;
#pragma unroll
    for (int i = 0; i < 32; i++) acc = fmaf(csf[ch4 * 256 + pg * 32 + i], xc[i * DIM], acc);
    gshf[ch4][pg][d] = acc;
  }
  __syncthreads();
  {
    int ch4 = t >> 8, tt = t & 255;
    if (tt < 32) {
      float s = 0.f;
#pragma unroll
      for (int pgi = 0; pgi < 8; pgi++) s += gshf[ch4][pgi][tt];
      gpartS[4 + ch4][tt] = s;
    }
    if (tt == 0) {
      gpartS[4 + ch4][32] = red32f[4 * ch4] + red32f[4 * ch4 + 1] + red32f[4 * ch4 + 2] + red32f[4 * ch4 + 3];
      gpartS[4 + ch4][33] = red33f[4 * ch4] + red33f[4 * ch4 + 1] + red33f[4 * ch4 + 2] + red33f[4 * ch4 + 3];
    }
  }
  __syncthreads();

  // ---- gfin: sequential over 8 chunks (matches R4 k_c) ----
  if (t < 34) {
    float s = 0.f;
    for (int j = 0; j < 8; j++) s += gpartS[j][t];
    gfin[t] = s;
  }
  __syncthreads();

  // ---- y2 for both points (identical fma chains to R4 k_c) ----
  float y20, y21;
  {
    const float4* p4 = (const float4*)(x + (base + t) * DIM);
    float ov = 0.f;
#pragma unroll
    for (int cc = 0; cc < 8; cc++) {
      float4 v = p4[cc];
      ov = fmaf(v.x, gfin[4 * cc + 0], ov);
      ov = fmaf(v.y, gfin[4 * cc + 1], ov);
      ov = fmaf(v.z, gfin[4 * cc + 2], ov);
      ov = fmaf(v.w, gfin[4 * cc + 3], ov);
    }
    ov += 3.f * dvA * gfin[32] + svA * gfin[33];
    ov /= nrmA;
    y20 = y1A / (1.f + ov);
  }
  {
    const float4* p4 = (const float4*)(x + (base + t + 1024) * DIM);
    float ov = 0.f;
#pragma unroll
    for (int cc = 0; cc < 8; cc++) {
      float4 v = p4[cc];
      ov = fmaf(v.x, gfin[4 * cc + 0], ov);
      ov = fmaf(v.y, gfin[4 * cc + 1], ov);
      ov = fmaf(v.z, gfin[4 * cc + 2], ov);
      ov = fmaf(v.w, gfin[4 * cc + 3], ov);
    }
    ov += 3.f * dvB * gfin[32] + svB * gfin[33];
    ov /= nrmB;
    y21 = y1B / (1.f + ov);
  }
  // ---- budget2: per-64-consecutive-point butterflies, chunked sums (R4 tree) ----
  {
    float p0 = y20, p1 = y21;
#pragma unroll
    for (int off = 32; off >= 1; off >>= 1) {
      p0 += __shfl_xor(p0, off);
      p1 += __shfl_xor(p1, off);
    }
    if (lane == 0) { red2[wid] = p0; red2[16 + wid] = p1; }
  }
  __syncthreads();
  if (t == 0) {
    float s = 0.f;
    for (int ch = 0; ch < 8; ch++) {
      float pch = red2[4 * ch] + red2[4 * ch + 1] + red2[4 * ch + 2] + red2[4 * ch + 3];
      s += pch;
    }
    bsh = fminf(KSEL / fmaxf(s, 1e-6f), 1.f);
  }
  __syncthreads();
  float scale2 = bsh;
  {
    float ys0 = y20 * scale2, ys1 = y21 * scale2;
    yv[t] = ys0; yv[t + 1024] = ys1;
    ystar[base + t] = ys0; ystar[base + t + 1024] = ys1;
  }
  __syncthreads();
  // ---- top-16 stage 1: wave w owns points [w*128, w*128+128) — exact selection ----
  {
    float lv0 = yv[wid * 128 + lane];      int li0 = wid * 128 + lane;
    float lv1 = yv[wid * 128 + 64 + lane]; int li1 = li0 + 64;
    for (int r = 0; r < KPROXY; r++) {
      float bv = lv0; int bi = li0;
      if (lv1 > bv) { bv = lv1; bi = li1; }   // li1 > li0: tie keeps lower
#pragma unroll
      for (int off = 1; off < 64; off <<= 1) {
        float ovv = __shfl_xor(bv, off);
        int oi = __shfl_xor(bi, off);
        if (ovv > bv || (ovv == bv && oi < bi)) { bv = ovv; bi = oi; }
      }
      if (lane == 0) { candv[wid * 16 + r] = bv; candi[wid * 16 + r] = bi; }
      if (li0 == bi) lv0 = -1e30f;
      if (li1 == bi) lv1 = -1e30f;
    }
  }
  __syncthreads();
  // ---- stage 2: wave 0 merges 256 candidates (ci0<ci1<ci2<ci3 by construction) ----
  if (wid == 0) {
    float cv0 = candv[lane], cv1 = candv[lane + 64];
    float cv2 = candv[lane + 128], cv3 = candv[lane + 192];
    int ci0 = candi[lane], ci1 = candi[lane + 64];
    int ci2 = candi[lane + 128], ci3 = candi[lane + 192];
    for (int r = 0; r < KPROXY; r++) {
      float bv = cv0; int bi = ci0;
      if (cv1 > bv) { bv = cv1; bi = ci1; }
      if (cv2 > bv) { bv = cv2; bi = ci2; }
      if (cv3 > bv) { bv = cv3; bi = ci3; }
#pragma unroll
      for (int off = 1; off < 64; off <<= 1) {
        float ovv = __shfl_xor(bv, off);
        int oi = __shfl_xor(bi, off);
        if (ovv > bv || (ovv == bv && oi < bi)) { bv = ovv; bi = oi; }
      }
      if (lane == 0) tix[r] = bi;
      if (ci0 == bi) cv0 = -1e30f;
      if (ci1 == bi) cv1 = -1e30f;
      if (ci2 == bi) cv2 = -1e30f;
      if (ci3 == bi) cv3 = -1e30f;
    }
  }
  __syncthreads();
  // ---- tokens: wave k handles selected row k — LDS-staged z (R4 pattern; no
  // shfl-from-inactive-lane UB) ----
  {
    int k = wid;
    int srow = tix[k];
    if (lane < 36) {
      float f;
      if (lane < 32) f = x[(base + srow) * DIM + lane];
      else if (lane < 35) f = sqrtf(__uint_as_float(nnd2[base + srow]));
      else f = 0.f;   // std of single NN distance is exactly 0
      sz[k][lane] = (f - mu[lane]) / sigma[lane];
    }
    __syncthreads();
    float lf = 0.f;
    if (lane < KLIFT) {
      float a = bl[lane];
#pragma unroll
      for (int d = 0; d < 36; d++) a = fmaf(sz[k][d], Wl[d * KLIFT + lane], a);
      lf = tanhf(a);
    }
    float o0 = bp[lane], o1 = bp[lane + 64], o2 = bp[lane + 128], o3 = bp[lane + 192];
#pragma unroll
    for (int j = 0; j < KLIFT; j++) {
      float lj = __shfl(lf, j);
      const float* wr = Wp + j * DMODEL + lane;
      o0 = fmaf(lj, wr[0], o0);
      o1 = fmaf(lj, wr[64], o1);
      o2 = fmaf(lj, wr[128], o2);
      o3 = fmaf(lj, wr[192], o3);
    }
    float* tp = tok + ((size_t)bb * KPROXY + k) * DMODEL + lane;
    tp[0] = o0; tp[64] = o1; tp[128] = o2; tp[192] = o3;
  }
}

extern "C" void kernel_launch(void* const* d_in, const int* in_sizes, int n_in,
                              void* d_out, int out_size, void* d_ws, size_t ws_size,
                              hipStream_t stream) {
  const float* x  = (const float*)d_in[0];
  const float* lt = (const float*)d_in[1];
  const float* W1 = (const float*)d_in[2];
  const float* b1 = (const float*)d_in[3];
  const float* W2 = (const float*)d_in[4];
  const float* b2 = (const float*)d_in[5];
  const float* mu = (const float*)d_in[6];
  const float* sg = (const float*)d_in[7];
  const float* Wl = (const float*)d_in[8];
  const float* bl = (const float*)d_in[9];
  const float* Wp = (const float*)d_in[10];
  const float* bp = (const float*)d_in[11];

  float* tok = (float*)d_out;
  float* ystar = tok + B * KPROXY * DMODEL;

  char* ws = (char*)d_ws;
  float* sal          = (float*)(ws);                    // 64 KB
  float* sq           = (float*)(ws + 65536);            // 64 KB
  unsigned* nnd2      = (unsigned*)(ws + 131072);        // 64 KB (float bits)
  float* partials1    = (float*)(ws + 196608);           // 64 f
  unsigned short* Xhi = (unsigned short*)(ws + 262144);  // 1 MB
  unsigned short* Xlo = (unsigned short*)(ws + 262144 + 1048576); // 1 MB

  k_prep<<<B * N / 256, 256, 0, stream>>>(x, W1, b1, W2, b2, lt, sal, sq, Xhi, Xlo, partials1, nnd2);
  k_nnd<<<B * 16 * 8, 256, 0, stream>>>(Xhi, Xlo, sq, nnd2);
  k_sel3<<<B, 1024, 0, stream>>>(x, sal, sq, nnd2, lt, partials1, mu, sg, Wl, bl, Wp, bp, tok, ystar);
}